// Round 9
// baseline (337.700 us; speedup 1.0000x reference)
//
#include <hip/hip_runtime.h>
#include <hip/hip_bf16.h>

// Problem constants (B=2, S=2048, DIM=1536, 12 heads x hd=128)
// Inputs fp32; OUTPUT fp32. Workspace ~94.8 MB (see kernel_launch).
#define SEQ    2048
#define TOK    4096          // B*S
#define DMODEL 1536
#define QKVROW 4608          // 3*DMODEL
#define HD     128
#define SCALE  0.08838834764831845f  // 1/sqrt(128)

#define NSPLIT 4
#define KRANGE (SEQ / NSPLIT)
#define NPAIR  12
#define ROWS_P (NPAIR * SEQ)
#define OPART_ELEMS ((size_t)ROWS_P * HD)

typedef __attribute__((ext_vector_type(8))) short short8;
typedef __attribute__((ext_vector_type(4))) short short4v;
typedef __attribute__((ext_vector_type(4))) float f32x4;

__device__ __forceinline__ float b2f(short s) {
    union { unsigned u; float f; } x;
    x.u = ((unsigned)(unsigned short)s) << 16;
    return x.f;
}
__device__ __forceinline__ short f2b(float f) {
    union { float f; unsigned u; } x; x.f = f;
    unsigned u = x.u;
    unsigned r = (u + 0x7fffu + ((u >> 16) & 1u)) >> 16;  // RNE
    return (short)r;
}

// async 16B global->LDS (m97 pattern). LDS dest: wave-uniform base + lane*16.
__device__ __forceinline__ void gld_lds16(const short* g, short* l) {
    __builtin_amdgcn_global_load_lds(
        (__attribute__((address_space(1))) void*)(g),
        (__attribute__((address_space(3))) void*)(l), 16, 0, 0);
}

// ---------------------------------------------------------------------------
// Fused prepass: x fp32->bf16, Wqkv/Wout fp32 -> transposed bf16.
// ---------------------------------------------------------------------------
#define CVT_BLOCKS  6144   // TOK*DMODEL / 1024
#define TQKV_BLOCKS 1728   // (QKVROW/64)*(DMODEL/64)
#define TOUT_BLOCKS 576    // (DMODEL/64)*(DMODEL/64)

__device__ __forceinline__ void transpose_tile(
    const float* __restrict__ W, short* __restrict__ WT,
    int K, int N, int k0, int n0, int t, short (*tile)[65])
{
    {
        int j  = t & 63;
        int i0 = (t >> 6) * 16;
        for (int ii = 0; ii < 16; ++ii)
            tile[i0 + ii][j] = f2b(W[(size_t)(k0 + i0 + ii) * N + n0 + j]);
    }
    __syncthreads();
    {
        int i  = t & 63;
        int j0 = (t >> 6) * 16;
        for (int jj = 0; jj < 16; ++jj)
            WT[(size_t)(n0 + j0 + jj) * K + k0 + i] = tile[i][j0 + jj];
    }
}

__global__ __launch_bounds__(256) void prepass_k(
    const float* __restrict__ x, const float* __restrict__ Wqkv,
    const float* __restrict__ Wout, short* __restrict__ xb,
    short* __restrict__ WqkvT, short* __restrict__ WoutT)
{
    __shared__ short tile[64][65];
    const int bid = blockIdx.x;
    const int t   = threadIdx.x;
    if (bid < CVT_BLOCKS) {
        int i = bid * 1024 + t * 4;
        float4 v = *(const float4*)(x + i);
        short4v b = { f2b(v.x), f2b(v.y), f2b(v.z), f2b(v.w) };
        *(short4v*)(xb + i) = b;
    } else if (bid < CVT_BLOCKS + TQKV_BLOCKS) {
        int tb = bid - CVT_BLOCKS;
        transpose_tile(Wqkv, WqkvT, DMODEL, QKVROW,
                       (tb / (QKVROW / 64)) * 64, (tb % (QKVROW / 64)) * 64, t, tile);
    } else {
        int tb = bid - (CVT_BLOCKS + TQKV_BLOCKS);
        transpose_tile(Wout, WoutT, DMODEL, DMODEL,
                       (tb / (DMODEL / 64)) * 64, (tb % (DMODEL / 64)) * 64, t, tile);
    }
}

// ---------------------------------------------------------------------------
// GEMM (r8 structure, LDS re-laid FRAGMENT-ORDER to kill the 8-way bank
// conflict -- the ONLY change vs the 98us r8 kernel):
//   C[M,N] = A[M,K] @ BT[N,K]^T + bias[N].
// Subtile st (16 rows x 32 k = 512 shorts): lane l holds row (l&15),
// k-cols (l>>4)*8..+8 at offset l*8 -> every ds_read_b128 is base+lane*16,
// conflict-free; global_load_lds takes the permutation on the GLOBAL address
// (m173).  Fragment values identical to the old [row][32] layout:
// af[i] = A[m0 + (wave>>1)*64 + i*16 + lo][kt + quad*8 + j].
// ---------------------------------------------------------------------------
template <bool OUT_BF16>
__global__ __launch_bounds__(256) void gemm_tn_k(
    const short* __restrict__ A, const short* __restrict__ BT,
    const float* __restrict__ bias, void* __restrict__ Cout,
    int M, int N, int K)
{
    __shared__ short As[8 * 512];   // 8 subtiles, fragment order
    __shared__ short Bs[8 * 512];

    const int t    = threadIdx.x;
    const int wave = t >> 6;
    const int lane = t & 63;
    const int quad = lane >> 4;
    const int lo   = lane & 15;
    const int m0   = blockIdx.y * 128;
    const int n0   = blockIdx.x * 128;
    const int wmst = (wave >> 1) * 4;   // A subtile group for reads
    const int wnst = (wave & 1) * 4;    // B subtile group for reads

    // Staging sources (fragment-order permutation on GLOBAL side):
    // wave w stages A subtiles {w, w+4} and B subtiles {w, w+4}.
    const short* aP0 = A  + (size_t)(m0 + wave * 16 + lo) * K + quad * 8;
    const short* aP1 = A  + (size_t)(m0 + 64 + wave * 16 + lo) * K + quad * 8;
    const short* bP0 = BT + (size_t)(n0 + wave * 16 + lo) * K + quad * 8;
    const short* bP1 = BT + (size_t)(n0 + 64 + wave * 16 + lo) * K + quad * 8;
    short* asD0 = As + wave * 512;
    short* asD1 = As + (4 + wave) * 512;
    short* bsD0 = Bs + wave * 512;
    short* bsD1 = Bs + (4 + wave) * 512;

    f32x4 acc[4][4];
    for (int i = 0; i < 4; ++i)
        for (int j = 0; j < 4; ++j)
            acc[i][j] = (f32x4){0.f, 0.f, 0.f, 0.f};

    for (int kt = 0; kt < K; kt += 32) {
        gld_lds16(aP0 + kt, asD0);
        gld_lds16(aP1 + kt, asD1);
        gld_lds16(bP0 + kt, bsD0);
        gld_lds16(bP1 + kt, bsD1);
        __syncthreads();

        short8 af[4], bfv[4];
        for (int i = 0; i < 4; ++i) {
            af[i]  = *(const short8*)(As + (wmst + i) * 512 + lane * 8);
            bfv[i] = *(const short8*)(Bs + (wnst + i) * 512 + lane * 8);
        }
        for (int mi = 0; mi < 4; ++mi)
            for (int ni = 0; ni < 4; ++ni)
                acc[mi][ni] = __builtin_amdgcn_mfma_f32_16x16x32_bf16(
                    af[mi], bfv[ni], acc[mi][ni], 0, 0, 0);
        __syncthreads();
    }

    for (int ni = 0; ni < 4; ++ni) {
        int col  = n0 + (wave & 1) * 64 + ni * 16 + lo;
        float bv = bias[col];
        for (int mi = 0; mi < 4; ++mi)
            for (int r = 0; r < 4; ++r) {
                int row = m0 + (wave >> 1) * 64 + mi * 16 + quad * 4 + r;
                float val = acc[mi][ni][r] + bv;
                if (OUT_BF16)
                    ((short*)Cout)[(size_t)row * N + col] = f2b(val);
                else
                    ((float*)Cout)[(size_t)row * N + col] = val;
            }
    }
}

// ---------------------------------------------------------------------------
// V transpose for full heads (h<6): vT[b][h][d][s] <- qkv V part.
// ---------------------------------------------------------------------------
#define VT_BLOCKS 768   // 12 bh * (32 s-tiles * 2 d-tiles)

__global__ __launch_bounds__(256) void vtrans_k(
    const short* __restrict__ qkv, short* __restrict__ vT)
{
    __shared__ short tile[64][65];
    const int bid = blockIdx.x;
    const int t   = threadIdx.x;
    const int bh  = bid >> 6;          // 0..11
    const int rem = bid & 63;
    const int st  = rem & 31, dt = rem >> 5;
    const int b   = bh / 6, h = bh % 6;
    const int s0  = st * 64, d0 = dt * 64;

    const short* src = qkv + (size_t)(b * SEQ + s0) * QKVROW + 2 * DMODEL + h * HD + d0;
    {
        int j = t & 63, i0 = (t >> 6) * 16;
        for (int ii = 0; ii < 16; ++ii)
            tile[i0 + ii][j] = src[(size_t)(i0 + ii) * QKVROW + j];
    }
    __syncthreads();
    {
        int i = t & 63, j0 = (t >> 6) * 16;
        short* dst = vT + ((size_t)(b * 6 + h) * HD + d0) * SEQ + s0;
        for (int jj = 0; jj < 16; ++jj)
            dst[(size_t)(j0 + jj) * SEQ + i] = tile[i][j0 + jj];
    }
}

// ---------------------------------------------------------------------------
// Flash attention full heads v2 (r8 verbatim): QBLK=128, split-K x4,
// fragment-order K/V staging via global_load_lds, V from vT, one barrier
// per k-tile, wave-private Pl.
// ---------------------------------------------------------------------------
#define KSP 136
#define VTP 44
#define PLP 40

__global__ __launch_bounds__(256, 3) void attn_full_v2(
    const short* __restrict__ qkv, const short* __restrict__ vT,
    short* __restrict__ Opart, float* __restrict__ lsum)
{
    const int pair = blockIdx.y;          // 12
    const int b    = pair / 6;
    const int h    = pair % 6;
    const int q0   = blockIdx.x * 128;    // 16 q-blocks
    const int kz   = blockIdx.z;          // 4
    const int t    = threadIdx.x;
    const int w    = t >> 6;
    const int lane = t & 63;
    const int quad = lane >> 4;
    const int lo   = lane & 15;

    __shared__ short KV[2][2][8][512];    // 32 KB
    __shared__ short Pl[4][2][16 * PLP];  // 10 KB, wave-private

    const short* base = qkv + (size_t)b * SEQ * QKVROW;

    short8 qf[2][4];
#pragma unroll
    for (int u = 0; u < 2; ++u) {
        const short* qp = base + (size_t)(q0 + w * 32 + u * 16 + lo) * QKVROW + h * HD;
#pragma unroll
        for (int c = 0; c < 4; ++c)
            qf[u][c] = *(const short8*)(qp + c * 32 + quad * 8);
    }

    f32x4 o[2][8];
#pragma unroll
    for (int u = 0; u < 2; ++u)
#pragma unroll
        for (int i = 0; i < 8; ++i)
            o[u][i] = (f32x4){0.f, 0.f, 0.f, 0.f};
    float lrow[2][4] = {{0.f, 0.f, 0.f, 0.f}, {0.f, 0.f, 0.f, 0.f}};

    const int k0s = kz * KRANGE;
    const short* kp0 = base + (size_t)(k0s + lo) * QKVROW      + DMODEL + h * HD + w * 32 + quad * 8;
    const short* kp1 = base + (size_t)(k0s + 16 + lo) * QKVROW + DMODEL + h * HD + w * 32 + quad * 8;
    const short* vbase = vT + ((size_t)(b * 6 + h) * HD) * SEQ;
    const short* vp0 = vbase + (size_t)(w * 16 + lo) * SEQ       + k0s + quad * 8;
    const short* vp1 = vbase + (size_t)((w + 4) * 16 + lo) * SEQ + k0s + quad * 8;

#define AFS_STG(SL, KT)                                                     \
    do {                                                                    \
        gld_lds16(kp0 + (size_t)(KT) * 32 * QKVROW, &KV[SL][0][w][0]);      \
        gld_lds16(kp1 + (size_t)(KT) * 32 * QKVROW, &KV[SL][0][w + 4][0]);  \
        gld_lds16(vp0 + (KT) * 32, &KV[SL][1][w][0]);                       \
        gld_lds16(vp1 + (KT) * 32, &KV[SL][1][w + 4][0]);                   \
    } while (0)

    AFS_STG(0, 0);
    __syncthreads();

    const int NT_ = KRANGE / 32;   // 16
#pragma unroll 1
    for (int kt = 0; kt < NT_; ++kt) {
        const int sl = kt & 1;
        if (kt + 1 < NT_) AFS_STG(sl ^ 1, kt + 1);

        f32x4 s[2][2];
        s[0][0] = s[0][1] = s[1][0] = s[1][1] = (f32x4){0.f, 0.f, 0.f, 0.f};
#pragma unroll
        for (int g = 0; g < 2; ++g)
#pragma unroll
            for (int c = 0; c < 4; ++c) {
                short8 kf = *(const short8*)(&KV[sl][0][g * 4 + c][lane * 8]);
                s[0][g] = __builtin_amdgcn_mfma_f32_16x16x32_bf16(qf[0][c], kf, s[0][g], 0, 0, 0);
                s[1][g] = __builtin_amdgcn_mfma_f32_16x16x32_bf16(qf[1][c], kf, s[1][g], 0, 0, 0);
            }

#pragma unroll
        for (int u = 0; u < 2; ++u)
#pragma unroll
            for (int g = 0; g < 2; ++g)
#pragma unroll
                for (int r = 0; r < 4; ++r) {
                    float p = __expf(s[u][g][r] * SCALE);
                    lrow[u][r] += p;
                    Pl[w][u][(quad * 4 + r) * PLP + g * 16 + lo] = f2b(p);
                }
        short8 pf0 = *(const short8*)(&Pl[w][0][lo * PLP + quad * 8]);
        short8 pf1 = *(const short8*)(&Pl[w][1][lo * PLP + quad * 8]);

#pragma unroll
        for (int ni = 0; ni < 8; ++ni) {
            short8 vf = *(const short8*)(&KV[sl][1][ni][lane * 8]);
            o[0][ni] = __builtin_amdgcn_mfma_f32_16x16x32_bf16(pf0, vf, o[0][ni], 0, 0, 0);
            o[1][ni] = __builtin_amdgcn_mfma_f32_16x16x32_bf16(pf1, vf, o[1][ni], 0, 0, 0);
        }
        __syncthreads();
    }
#undef AFS_STG

    for (int u = 0; u < 2; ++u)
        for (int r = 0; r < 4; ++r)
            for (int off = 1; off < 16; off <<= 1)
                lrow[u][r] += __shfl_xor(lrow[u][r], off, 64);

#pragma unroll
    for (int u = 0; u < 2; ++u)
        for (int ni = 0; ni < 8; ++ni)
            for (int r = 0; r < 4; ++r) {
                int grow = pair * SEQ + q0 + w * 32 + u * 16 + quad * 4 + r;
                Opart[(size_t)kz * OPART_ELEMS + (size_t)grow * HD + ni * 16 + lo] =
                    f2b(o[u][ni][r]);
            }
    if (lo == 0)
        for (int u = 0; u < 2; ++u)
            for (int r = 0; r < 4; ++r) {
                int grow = pair * SEQ + q0 + w * 32 + u * 16 + quad * 4 + r;
                lsum[kz * ROWS_P + grow] = lrow[u][r];
            }
}

// ---------------------------------------------------------------------------
// Local heads (h=6..9), banded-flash MFMA.  (r0 verbatim; tiny -- 4 tiles.)
// ---------------------------------------------------------------------------
__global__ __launch_bounds__(256) void attn_local_mfma(
    const short* __restrict__ qkv, short* __restrict__ att)
{
    const int pair = blockIdx.y;          // 0..7
    const int b    = pair >> 2;
    const int h    = 6 + (pair & 3);
    const int q0   = blockIdx.x * 64;
    const int t    = threadIdx.x;
    const int wave = t >> 6;
    const int lane = t & 63;
    const int quad = lane >> 4;
    const int lo   = lane & 15;

    __shared__ short Ks[32 * KSP];
    __shared__ short Vr[32 * KSP];
    __shared__ short Vt[128 * VTP];
    __shared__ short Pl[4][16 * PLP];

    const short* base = qkv + (size_t)b * SEQ * QKVROW;

    short8 qf[4];
    {
        int qrow = q0 + wave * 16 + lo;
        const short* qp = base + (size_t)qrow * QKVROW + h * HD;
        for (int c = 0; c < 4; ++c)
            qf[c] = *(const short8*)(qp + c * 32 + quad * 8);
    }

    f32x4 o[8];
    for (int i = 0; i < 8; ++i) o[i] = (f32x4){0.f, 0.f, 0.f, 0.f};
    float lrow[4] = {0.f, 0.f, 0.f, 0.f};

    const int skey = t >> 3;
    const int sdc  = (t & 7) * 16;
    const int thd  = t & 127;
    const int tkc  = (t >> 7) * 16;
    const int irow = q0 + wave * 16 + quad * 4;   // query row = irow + r

    const int ks = max(0, q0 - 32);
    const int ke = min(SEQ, q0 + 96);
    for (int k0 = ks; k0 < ke; k0 += 32) {
        {
            const short* kro = base + (size_t)(k0 + skey) * QKVROW + DMODEL     + h * HD + sdc;
            const short* vro = base + (size_t)(k0 + skey) * QKVROW + 2 * DMODEL + h * HD + sdc;
            short8 ka = *(const short8*)kro;
            short8 kb = *(const short8*)(kro + 8);
            short8 va = *(const short8*)vro;
            short8 vb = *(const short8*)(vro + 8);
            *(short8*)(Ks + skey * KSP + sdc)     = ka;
            *(short8*)(Ks + skey * KSP + sdc + 8) = kb;
            *(short8*)(Vr + skey * KSP + sdc)     = va;
            *(short8*)(Vr + skey * KSP + sdc + 8) = vb;
        }
        __syncthreads();   // B1

        {
            short8 x0, x1;
            for (int j = 0; j < 8; ++j) x0[j] = Vr[(tkc + j) * KSP + thd];
            for (int j = 0; j < 8; ++j) x1[j] = Vr[(tkc + 8 + j) * KSP + thd];
            *(short8*)(Vt + thd * VTP + tkc)     = x0;
            *(short8*)(Vt + thd * VTP + tkc + 8) = x1;
        }

        f32x4 s[2];
        s[0] = (f32x4){0.f, 0.f, 0.f, 0.f};
        s[1] = (f32x4){0.f, 0.f, 0.f, 0.f};
        for (int g = 0; g < 2; ++g)
            for (int c = 0; c < 4; ++c) {
                short8 kf = *(const short8*)(Ks + (g * 16 + lo) * KSP + c * 32 + quad * 8);
                s[g] = __builtin_amdgcn_mfma_f32_16x16x32_bf16(qf[c], kf, s[g], 0, 0, 0);
            }

        // mask |i-j|<=32, p=exp(s*scale) else 0
        for (int g = 0; g < 2; ++g)
            for (int r = 0; r < 4; ++r) {
                int j = k0 + g * 16 + lo;
                int d = irow + r - j;
                float p = (d >= -32 && d <= 32) ? __expf(s[g][r] * SCALE) : 0.f;
                lrow[r] += p;
                Pl[wave][(quad * 4 + r) * PLP + g * 16 + lo] = f2b(p);
            }
        __syncthreads();   // B2

        short8 pf = *(const short8*)(&Pl[wave][lo * PLP + quad * 8]);
        for (int ni = 0; ni < 8; ++ni) {
            short8 vf = *(const short8*)(Vt + (ni * 16 + lo) * VTP + quad * 8);
            o[ni] = __builtin_amdgcn_mfma_f32_16x16x32_bf16(pf, vf, o[ni], 0, 0, 0);
        }
    }

    for (int r = 0; r < 4; ++r)
        for (int off = 1; off < 16; off <<= 1)
            lrow[r] += __shfl_xor(lrow[r], off, 64);

    for (int ni = 0; ni < 8; ++ni)
        for (int r = 0; r < 4; ++r) {
            int row = irow + r;
            size_t off = ((size_t)(b * SEQ + row)) * DMODEL + h * HD + ni * 16 + lo;
            att[off] = f2b(o[ni][r] / lrow[r]);
        }
}

// ---------------------------------------------------------------------------
// Fused post-attention: merge (heads 0-5) + global (10-11).  (unchanged)
// ---------------------------------------------------------------------------
#define MERGE_BLOCKS  12288   // NPAIR*SEQ*HD/256
#define GLOBAL_BLOCKS 2048    // (SEQ/4)*4

__global__ __launch_bounds__(256) void postattn_k(
    const short* __restrict__ qkv, const short* __restrict__ Opart,
    const float* __restrict__ lsum, short* __restrict__ att)
{
    const int bid  = blockIdx.x;
    const int t    = threadIdx.x;
    const int wave = t >> 6;
    const int lane = t & 63;

    if (bid < MERGE_BLOCKS) {
        int idx  = bid * 256 + t;
        int pair = idx >> 18;
        int q    = (idx >> 7) & (SEQ - 1);
        int hd   = idx & (HD - 1);
        int row  = pair * SEQ + q;
        float osum = 0.f, ls = 0.f;
        for (int z = 0; z < NSPLIT; ++z) {
            ls   += lsum[z * ROWS_P + row];
            osum += b2f(Opart[(size_t)z * OPART_ELEMS + (size_t)row * HD + hd]);
        }
        int b = pair / 6, h = pair % 6;
        att[((size_t)(b * SEQ + q)) * DMODEL + h * HD + hd] = f2b(osum / ls);
    } else {
        int gb   = bid - MERGE_BLOCKS;
        int pair = gb >> 9;               // 0..3
        int q    = (gb & 511) * 4 + wave;
        int b    = pair >> 1;
        int h    = 10 + (pair & 1);

        const short* base = qkv + (size_t)b * SEQ * QKVROW;
        const short* qp   = base + (size_t)q * QKVROW + h * HD;
        const short* k0   = base + DMODEL + h * HD;
        const short* k1   = base + (size_t)(SEQ - 1) * QKVROW + DMODEL + h * HD;

        float s0 = fmaf(b2f(qp[lane]), b2f(k0[lane]),
                   b2f(qp[lane + 64]) * b2f(k0[lane + 64]));
        float s1 = fmaf(b2f(qp[lane]), b2f(k1[lane]),
                   b2f(qp[lane + 64]) * b2f(k1[lane + 64]));
        for (int off = 1; off < 64; off <<= 1) {
            s0 += __shfl_xor(s0, off, 64);
            s1 += __shfl_xor(s1, off, 64);
        }
        s0 *= SCALE; s1 *= SCALE;
        float m  = fmaxf(s0, s1);
        float e0 = __expf(s0 - m), e1 = __expf(s1 - m);
        float inv = 1.f / (e0 + e1);
        float p0 = e0 * inv, p1 = e1 * inv;

        const short* v0 = base + 2 * DMODEL + h * HD;
        const short* v1 = base + (size_t)(SEQ - 1) * QKVROW + 2 * DMODEL + h * HD;
        size_t ob = ((size_t)(b * SEQ + q)) * DMODEL + h * HD;
        att[ob + lane]      = f2b(fmaf(p0, b2f(v0[lane]),      p1 * b2f(v1[lane])));
        att[ob + lane + 64] = f2b(fmaf(p0, b2f(v0[lane + 64]), p1 * b2f(v1[lane + 64])));
    }
}

// ---------------------------------------------------------------------------
extern "C" void kernel_launch(void* const* d_in, const int* in_sizes, int n_in,
                              void* d_out, int out_size, void* d_ws, size_t ws_size,
                              hipStream_t stream) {
    const float* x    = (const float*)d_in[0];
    const float* Wqkv = (const float*)d_in[1];
    const float* bqkv = (const float*)d_in[2];
    const float* Wout = (const float*)d_in[3];
    const float* bout = (const float*)d_in[4];

    // ws layout (~94.8 MB): att aliases xb (xb dead after GEMM1);
    // vT (6.3 MB, V^T of full heads) aliases WqkvT (dead after GEMM1).
    char* p = (char*)d_ws;
    short* qkv   = (short*)p;  p += (size_t)TOK * QKVROW * 2;      // 37.75 MB
    short* Opart = (short*)p;  p += OPART_ELEMS * NSPLIT * 2;      // 25.17 MB
    float* lsum  = (float*)p;  p += (size_t)ROWS_P * NSPLIT * 4;   // 0.39 MB
    short* xb    = (short*)p;  p += (size_t)TOK * DMODEL * 2;      // 12.58 MB
    short* att   = xb;                                             // alias
    short* WqkvT = (short*)p;  p += (size_t)QKVROW * DMODEL * 2;   // 14.16 MB
    short* vT    = WqkvT;                                          // alias (6.29 MB used)
    short* WoutT = (short*)p;                                      // 4.72 MB

    // 0) fused prepass
    prepass_k<<<dim3(CVT_BLOCKS + TQKV_BLOCKS + TOUT_BLOCKS), 256, 0, stream>>>(
        x, Wqkv, Wout, xb, WqkvT, WoutT);
    // 1) QKV = x @ Wqkv + bqkv   (bf16 out)
    gemm_tn_k<true><<<dim3(QKVROW / 128, TOK / 128), 256, 0, stream>>>(
        xb, WqkvT, bqkv, (void*)qkv, TOK, QKVROW, DMODEL);
    // 2) V^T for full heads (WqkvT now dead -> reuse as vT)
    vtrans_k<<<dim3(VT_BLOCKS), 256, 0, stream>>>(qkv, vT);
    // 3) attention: full v2 + banded local MFMA + fused merge/global
    attn_full_v2<<<dim3(SEQ / 128, NPAIR, NSPLIT), 256, 0, stream>>>(
        qkv, vT, Opart, lsum);
    attn_local_mfma<<<dim3(SEQ / 64, 8), 256, 0, stream>>>(qkv, att);
    postattn_k<<<dim3(MERGE_BLOCKS + GLOBAL_BLOCKS), 256, 0, stream>>>(
        qkv, Opart, lsum, att);
    // 4) out = att @ Wout + bout  (fp32 out)
    gemm_tn_k<false><<<dim3(DMODEL / 128, TOK / 128), 256, 0, stream>>>(
        att, WoutT, bout, d_out, TOK, DMODEL, DMODEL);
}

// Round 10
// 293.596 us; speedup vs baseline: 1.1502x; 1.1502x over previous
//
#include <hip/hip_runtime.h>
#include <hip/hip_bf16.h>

// Problem constants (B=2, S=2048, DIM=1536, 12 heads x hd=128)
// Inputs fp32; OUTPUT fp32. Workspace ~94.8 MB (see kernel_launch).
#define SEQ    2048
#define TOK    4096          // B*S
#define DMODEL 1536
#define QKVROW 4608          // 3*DMODEL
#define HD     128
#define SCALE  0.08838834764831845f  // 1/sqrt(128)

#define NSPLIT 4
#define KRANGE (SEQ / NSPLIT)
#define NPAIR  12
#define ROWS_P (NPAIR * SEQ)
#define OPART_ELEMS ((size_t)ROWS_P * HD)

typedef __attribute__((ext_vector_type(8))) short short8;
typedef __attribute__((ext_vector_type(4))) short short4v;
typedef __attribute__((ext_vector_type(4))) float f32x4;

__device__ __forceinline__ float b2f(short s) {
    union { unsigned u; float f; } x;
    x.u = ((unsigned)(unsigned short)s) << 16;
    return x.f;
}
__device__ __forceinline__ short f2b(float f) {
    union { float f; unsigned u; } x; x.f = f;
    unsigned u = x.u;
    unsigned r = (u + 0x7fffu + ((u >> 16) & 1u)) >> 16;  // RNE
    return (short)r;
}

// async 16B global->LDS (m97 pattern). LDS dest: wave-uniform base + lane*16.
__device__ __forceinline__ void gld_lds16(const short* g, short* l) {
    __builtin_amdgcn_global_load_lds(
        (__attribute__((address_space(1))) void*)(g),
        (__attribute__((address_space(3))) void*)(l), 16, 0, 0);
}

// ---------------------------------------------------------------------------
// Fused prepass: x fp32->bf16, Wqkv/Wout fp32 -> transposed bf16.
// ---------------------------------------------------------------------------
#define CVT_BLOCKS  6144   // TOK*DMODEL / 1024
#define TQKV_BLOCKS 1728   // (QKVROW/64)*(DMODEL/64)
#define TOUT_BLOCKS 576    // (DMODEL/64)*(DMODEL/64)

__device__ __forceinline__ void transpose_tile(
    const float* __restrict__ W, short* __restrict__ WT,
    int K, int N, int k0, int n0, int t, short (*tile)[65])
{
    {
        int j  = t & 63;
        int i0 = (t >> 6) * 16;
        for (int ii = 0; ii < 16; ++ii)
            tile[i0 + ii][j] = f2b(W[(size_t)(k0 + i0 + ii) * N + n0 + j]);
    }
    __syncthreads();
    {
        int i  = t & 63;
        int j0 = (t >> 6) * 16;
        for (int jj = 0; jj < 16; ++jj)
            WT[(size_t)(n0 + j0 + jj) * K + k0 + i] = tile[i][j0 + jj];
    }
}

__global__ __launch_bounds__(256) void prepass_k(
    const float* __restrict__ x, const float* __restrict__ Wqkv,
    const float* __restrict__ Wout, short* __restrict__ xb,
    short* __restrict__ WqkvT, short* __restrict__ WoutT)
{
    __shared__ short tile[64][65];
    const int bid = blockIdx.x;
    const int t   = threadIdx.x;
    if (bid < CVT_BLOCKS) {
        int i = bid * 1024 + t * 4;
        float4 v = *(const float4*)(x + i);
        short4v b = { f2b(v.x), f2b(v.y), f2b(v.z), f2b(v.w) };
        *(short4v*)(xb + i) = b;
    } else if (bid < CVT_BLOCKS + TQKV_BLOCKS) {
        int tb = bid - CVT_BLOCKS;
        transpose_tile(Wqkv, WqkvT, DMODEL, QKVROW,
                       (tb / (QKVROW / 64)) * 64, (tb % (QKVROW / 64)) * 64, t, tile);
    } else {
        int tb = bid - (CVT_BLOCKS + TQKV_BLOCKS);
        transpose_tile(Wout, WoutT, DMODEL, DMODEL,
                       (tb / (DMODEL / 64)) * 64, (tb % (DMODEL / 64)) * 64, t, tile);
    }
}

// ---------------------------------------------------------------------------
// GEMM (r8 structure + ROTATE-SWIZZLED fragment-order LDS):
//   C[M,N] = A[M,K] @ BT[N,K]^T + bias[N].
// Slot map within a 16-row x 32-k subtile (slots = 16B units):
//   place(r,s) = 4r + ((s + (r>>1)) & 3)      r=row 0..15, s=8-short seg 0..3
// STAGING (lane l writes slot l via gld_lds16): fetches row l>>2, seg
//   ((l&3) - (l>>3)) & 3  -> each 4-lane group reads ONE row's contiguous
//   64B (r8's coalescing-proven address set, just rotated within the row).
// READ (lane l needs row lo, seg quad): slot 4*lo + ((quad+(lo>>1))&3);
//   within every 8-lane group residues mod 8 are all distinct -> conflict-
//   free per the r8/r9-measured b128 model (r8: {0,4} only -> 4-way, 7.08M;
//   r9: lane-linear -> 0).  Fragments bit-identical to r8/r9.
// ---------------------------------------------------------------------------
template <bool OUT_BF16>
__global__ __launch_bounds__(256) void gemm_tn_k(
    const short* __restrict__ A, const short* __restrict__ BT,
    const float* __restrict__ bias, void* __restrict__ Cout,
    int M, int N, int K)
{
    __shared__ short As[8 * 512];   // 8 subtiles, rotate-swizzled frag order
    __shared__ short Bs[8 * 512];

    const int t    = threadIdx.x;
    const int wave = t >> 6;
    const int lane = t & 63;
    const int quad = lane >> 4;
    const int lo   = lane & 15;
    const int m0   = blockIdx.y * 128;
    const int n0   = blockIdx.x * 128;
    const int wmst = (wave >> 1) * 4;   // A subtile group for reads
    const int wnst = (wave & 1) * 4;    // B subtile group for reads

    // Staging sources: lane l supplies (row = l>>2, seg rotated by row>>1).
    const int srow = lane >> 2;                        // 0..15
    const int scol = (((lane & 3) - (srow >> 1)) & 3) * 8;

    const short* aP0 = A  + (size_t)(m0 + wave * 16 + srow) * K + scol;
    const short* aP1 = A  + (size_t)(m0 + 64 + wave * 16 + srow) * K + scol;
    const short* bP0 = BT + (size_t)(n0 + wave * 16 + srow) * K + scol;
    const short* bP1 = BT + (size_t)(n0 + 64 + wave * 16 + srow) * K + scol;
    short* asD0 = As + wave * 512;
    short* asD1 = As + (4 + wave) * 512;
    short* bsD0 = Bs + wave * 512;
    short* bsD1 = Bs + (4 + wave) * 512;

    // Read offset (shorts): place(lo, quad) * 8
    const int rdoff = (4 * lo + ((quad + (lo >> 1)) & 3)) * 8;

    f32x4 acc[4][4];
    for (int i = 0; i < 4; ++i)
        for (int j = 0; j < 4; ++j)
            acc[i][j] = (f32x4){0.f, 0.f, 0.f, 0.f};

    for (int kt = 0; kt < K; kt += 32) {
        gld_lds16(aP0 + kt, asD0);
        gld_lds16(aP1 + kt, asD1);
        gld_lds16(bP0 + kt, bsD0);
        gld_lds16(bP1 + kt, bsD1);
        __syncthreads();

        short8 af[4], bfv[4];
        for (int i = 0; i < 4; ++i) {
            af[i]  = *(const short8*)(As + (wmst + i) * 512 + rdoff);
            bfv[i] = *(const short8*)(Bs + (wnst + i) * 512 + rdoff);
        }
        for (int mi = 0; mi < 4; ++mi)
            for (int ni = 0; ni < 4; ++ni)
                acc[mi][ni] = __builtin_amdgcn_mfma_f32_16x16x32_bf16(
                    af[mi], bfv[ni], acc[mi][ni], 0, 0, 0);
        __syncthreads();
    }

    for (int ni = 0; ni < 4; ++ni) {
        int col  = n0 + (wave & 1) * 64 + ni * 16 + lo;
        float bv = bias[col];
        for (int mi = 0; mi < 4; ++mi)
            for (int r = 0; r < 4; ++r) {
                int row = m0 + (wave >> 1) * 64 + mi * 16 + quad * 4 + r;
                float val = acc[mi][ni][r] + bv;
                if (OUT_BF16)
                    ((short*)Cout)[(size_t)row * N + col] = f2b(val);
                else
                    ((float*)Cout)[(size_t)row * N + col] = val;
            }
    }
}

// ---------------------------------------------------------------------------
// V transpose for full heads (h<6): vT[b][h][d][s] <- qkv V part.
// ---------------------------------------------------------------------------
#define VT_BLOCKS 768   // 12 bh * (32 s-tiles * 2 d-tiles)

__global__ __launch_bounds__(256) void vtrans_k(
    const short* __restrict__ qkv, short* __restrict__ vT)
{
    __shared__ short tile[64][65];
    const int bid = blockIdx.x;
    const int t   = threadIdx.x;
    const int bh  = bid >> 6;          // 0..11
    const int rem = bid & 63;
    const int st  = rem & 31, dt = rem >> 5;
    const int b   = bh / 6, h = bh % 6;
    const int s0  = st * 64, d0 = dt * 64;

    const short* src = qkv + (size_t)(b * SEQ + s0) * QKVROW + 2 * DMODEL + h * HD + d0;
    {
        int j = t & 63, i0 = (t >> 6) * 16;
        for (int ii = 0; ii < 16; ++ii)
            tile[i0 + ii][j] = src[(size_t)(i0 + ii) * QKVROW + j];
    }
    __syncthreads();
    {
        int i = t & 63, j0 = (t >> 6) * 16;
        short* dst = vT + ((size_t)(b * 6 + h) * HD + d0) * SEQ + s0;
        for (int jj = 0; jj < 16; ++jj)
            dst[(size_t)(j0 + jj) * SEQ + i] = tile[i][j0 + jj];
    }
}

// ---------------------------------------------------------------------------
// Flash attention full heads v2 (r8 verbatim): QBLK=128, split-K x4,
// fragment-order K/V staging via global_load_lds, V from vT, one barrier
// per k-tile, wave-private Pl.
// ---------------------------------------------------------------------------
#define KSP 136
#define VTP 44
#define PLP 40

__global__ __launch_bounds__(256, 3) void attn_full_v2(
    const short* __restrict__ qkv, const short* __restrict__ vT,
    short* __restrict__ Opart, float* __restrict__ lsum)
{
    const int pair = blockIdx.y;          // 12
    const int b    = pair / 6;
    const int h    = pair % 6;
    const int q0   = blockIdx.x * 128;    // 16 q-blocks
    const int kz   = blockIdx.z;          // 4
    const int t    = threadIdx.x;
    const int w    = t >> 6;
    const int lane = t & 63;
    const int quad = lane >> 4;
    const int lo   = lane & 15;

    __shared__ short KV[2][2][8][512];    // 32 KB
    __shared__ short Pl[4][2][16 * PLP];  // 10 KB, wave-private

    const short* base = qkv + (size_t)b * SEQ * QKVROW;

    short8 qf[2][4];
#pragma unroll
    for (int u = 0; u < 2; ++u) {
        const short* qp = base + (size_t)(q0 + w * 32 + u * 16 + lo) * QKVROW + h * HD;
#pragma unroll
        for (int c = 0; c < 4; ++c)
            qf[u][c] = *(const short8*)(qp + c * 32 + quad * 8);
    }

    f32x4 o[2][8];
#pragma unroll
    for (int u = 0; u < 2; ++u)
#pragma unroll
        for (int i = 0; i < 8; ++i)
            o[u][i] = (f32x4){0.f, 0.f, 0.f, 0.f};
    float lrow[2][4] = {{0.f, 0.f, 0.f, 0.f}, {0.f, 0.f, 0.f, 0.f}};

    const int k0s = kz * KRANGE;
    const short* kp0 = base + (size_t)(k0s + lo) * QKVROW      + DMODEL + h * HD + w * 32 + quad * 8;
    const short* kp1 = base + (size_t)(k0s + 16 + lo) * QKVROW + DMODEL + h * HD + w * 32 + quad * 8;
    const short* vbase = vT + ((size_t)(b * 6 + h) * HD) * SEQ;
    const short* vp0 = vbase + (size_t)(w * 16 + lo) * SEQ       + k0s + quad * 8;
    const short* vp1 = vbase + (size_t)((w + 4) * 16 + lo) * SEQ + k0s + quad * 8;

#define AFS_STG(SL, KT)                                                     \
    do {                                                                    \
        gld_lds16(kp0 + (size_t)(KT) * 32 * QKVROW, &KV[SL][0][w][0]);      \
        gld_lds16(kp1 + (size_t)(KT) * 32 * QKVROW, &KV[SL][0][w + 4][0]);  \
        gld_lds16(vp0 + (KT) * 32, &KV[SL][1][w][0]);                       \
        gld_lds16(vp1 + (KT) * 32, &KV[SL][1][w + 4][0]);                   \
    } while (0)

    AFS_STG(0, 0);
    __syncthreads();

    const int NT_ = KRANGE / 32;   // 16
#pragma unroll 1
    for (int kt = 0; kt < NT_; ++kt) {
        const int sl = kt & 1;
        if (kt + 1 < NT_) AFS_STG(sl ^ 1, kt + 1);

        f32x4 s[2][2];
        s[0][0] = s[0][1] = s[1][0] = s[1][1] = (f32x4){0.f, 0.f, 0.f, 0.f};
#pragma unroll
        for (int g = 0; g < 2; ++g)
#pragma unroll
            for (int c = 0; c < 4; ++c) {
                short8 kf = *(const short8*)(&KV[sl][0][g * 4 + c][lane * 8]);
                s[0][g] = __builtin_amdgcn_mfma_f32_16x16x32_bf16(qf[0][c], kf, s[0][g], 0, 0, 0);
                s[1][g] = __builtin_amdgcn_mfma_f32_16x16x32_bf16(qf[1][c], kf, s[1][g], 0, 0, 0);
            }

#pragma unroll
        for (int u = 0; u < 2; ++u)
#pragma unroll
            for (int g = 0; g < 2; ++g)
#pragma unroll
                for (int r = 0; r < 4; ++r) {
                    float p = __expf(s[u][g][r] * SCALE);
                    lrow[u][r] += p;
                    Pl[w][u][(quad * 4 + r) * PLP + g * 16 + lo] = f2b(p);
                }
        short8 pf0 = *(const short8*)(&Pl[w][0][lo * PLP + quad * 8]);
        short8 pf1 = *(const short8*)(&Pl[w][1][lo * PLP + quad * 8]);

#pragma unroll
        for (int ni = 0; ni < 8; ++ni) {
            short8 vf = *(const short8*)(&KV[sl][1][ni][lane * 8]);
            o[0][ni] = __builtin_amdgcn_mfma_f32_16x16x32_bf16(pf0, vf, o[0][ni], 0, 0, 0);
            o[1][ni] = __builtin_amdgcn_mfma_f32_16x16x32_bf16(pf1, vf, o[1][ni], 0, 0, 0);
        }
        __syncthreads();
    }
#undef AFS_STG

    for (int u = 0; u < 2; ++u)
        for (int r = 0; r < 4; ++r)
            for (int off = 1; off < 16; off <<= 1)
                lrow[u][r] += __shfl_xor(lrow[u][r], off, 64);

#pragma unroll
    for (int u = 0; u < 2; ++u)
        for (int ni = 0; ni < 8; ++ni)
            for (int r = 0; r < 4; ++r) {
                int grow = pair * SEQ + q0 + w * 32 + u * 16 + quad * 4 + r;
                Opart[(size_t)kz * OPART_ELEMS + (size_t)grow * HD + ni * 16 + lo] =
                    f2b(o[u][ni][r]);
            }
    if (lo == 0)
        for (int u = 0; u < 2; ++u)
            for (int r = 0; r < 4; ++r) {
                int grow = pair * SEQ + q0 + w * 32 + u * 16 + quad * 4 + r;
                lsum[kz * ROWS_P + grow] = lrow[u][r];
            }
}

// ---------------------------------------------------------------------------
// Local heads (h=6..9), banded-flash MFMA.  (r0 verbatim; tiny -- 4 tiles.)
// ---------------------------------------------------------------------------
__global__ __launch_bounds__(256) void attn_local_mfma(
    const short* __restrict__ qkv, short* __restrict__ att)
{
    const int pair = blockIdx.y;          // 0..7
    const int b    = pair >> 2;
    const int h    = 6 + (pair & 3);
    const int q0   = blockIdx.x * 64;
    const int t    = threadIdx.x;
    const int wave = t >> 6;
    const int lane = t & 63;
    const int quad = lane >> 4;
    const int lo   = lane & 15;

    __shared__ short Ks[32 * KSP];
    __shared__ short Vr[32 * KSP];
    __shared__ short Vt[128 * VTP];
    __shared__ short Pl[4][16 * PLP];

    const short* base = qkv + (size_t)b * SEQ * QKVROW;

    short8 qf[4];
    {
        int qrow = q0 + wave * 16 + lo;
        const short* qp = base + (size_t)qrow * QKVROW + h * HD;
        for (int c = 0; c < 4; ++c)
            qf[c] = *(const short8*)(qp + c * 32 + quad * 8);
    }

    f32x4 o[8];
    for (int i = 0; i < 8; ++i) o[i] = (f32x4){0.f, 0.f, 0.f, 0.f};
    float lrow[4] = {0.f, 0.f, 0.f, 0.f};

    const int skey = t >> 3;
    const int sdc  = (t & 7) * 16;
    const int thd  = t & 127;
    const int tkc  = (t >> 7) * 16;
    const int irow = q0 + wave * 16 + quad * 4;   // query row = irow + r

    const int ks = max(0, q0 - 32);
    const int ke = min(SEQ, q0 + 96);
    for (int k0 = ks; k0 < ke; k0 += 32) {
        {
            const short* kro = base + (size_t)(k0 + skey) * QKVROW + DMODEL     + h * HD + sdc;
            const short* vro = base + (size_t)(k0 + skey) * QKVROW + 2 * DMODEL + h * HD + sdc;
            short8 ka = *(const short8*)kro;
            short8 kb = *(const short8*)(kro + 8);
            short8 va = *(const short8*)vro;
            short8 vb = *(const short8*)(vro + 8);
            *(short8*)(Ks + skey * KSP + sdc)     = ka;
            *(short8*)(Ks + skey * KSP + sdc + 8) = kb;
            *(short8*)(Vr + skey * KSP + sdc)     = va;
            *(short8*)(Vr + skey * KSP + sdc + 8) = vb;
        }
        __syncthreads();   // B1

        {
            short8 x0, x1;
            for (int j = 0; j < 8; ++j) x0[j] = Vr[(tkc + j) * KSP + thd];
            for (int j = 0; j < 8; ++j) x1[j] = Vr[(tkc + 8 + j) * KSP + thd];
            *(short8*)(Vt + thd * VTP + tkc)     = x0;
            *(short8*)(Vt + thd * VTP + tkc + 8) = x1;
        }

        f32x4 s[2];
        s[0] = (f32x4){0.f, 0.f, 0.f, 0.f};
        s[1] = (f32x4){0.f, 0.f, 0.f, 0.f};
        for (int g = 0; g < 2; ++g)
            for (int c = 0; c < 4; ++c) {
                short8 kf = *(const short8*)(Ks + (g * 16 + lo) * KSP + c * 32 + quad * 8);
                s[g] = __builtin_amdgcn_mfma_f32_16x16x32_bf16(qf[c], kf, s[g], 0, 0, 0);
            }

        // mask |i-j|<=32, p=exp(s*scale) else 0
        for (int g = 0; g < 2; ++g)
            for (int r = 0; r < 4; ++r) {
                int j = k0 + g * 16 + lo;
                int d = irow + r - j;
                float p = (d >= -32 && d <= 32) ? __expf(s[g][r] * SCALE) : 0.f;
                lrow[r] += p;
                Pl[wave][(quad * 4 + r) * PLP + g * 16 + lo] = f2b(p);
            }
        __syncthreads();   // B2

        short8 pf = *(const short8*)(&Pl[wave][lo * PLP + quad * 8]);
        for (int ni = 0; ni < 8; ++ni) {
            short8 vf = *(const short8*)(Vt + (ni * 16 + lo) * VTP + quad * 8);
            o[ni] = __builtin_amdgcn_mfma_f32_16x16x32_bf16(pf, vf, o[ni], 0, 0, 0);
        }
    }

    for (int r = 0; r < 4; ++r)
        for (int off = 1; off < 16; off <<= 1)
            lrow[r] += __shfl_xor(lrow[r], off, 64);

    for (int ni = 0; ni < 8; ++ni)
        for (int r = 0; r < 4; ++r) {
            int row = irow + r;
            size_t off = ((size_t)(b * SEQ + row)) * DMODEL + h * HD + ni * 16 + lo;
            att[off] = f2b(o[ni][r] / lrow[r]);
        }
}

// ---------------------------------------------------------------------------
// Fused post-attention: merge (heads 0-5) + global (10-11).  (unchanged)
// ---------------------------------------------------------------------------
#define MERGE_BLOCKS  12288   // NPAIR*SEQ*HD/256
#define GLOBAL_BLOCKS 2048    // (SEQ/4)*4

__global__ __launch_bounds__(256) void postattn_k(
    const short* __restrict__ qkv, const short* __restrict__ Opart,
    const float* __restrict__ lsum, short* __restrict__ att)
{
    const int bid  = blockIdx.x;
    const int t    = threadIdx.x;
    const int wave = t >> 6;
    const int lane = t & 63;

    if (bid < MERGE_BLOCKS) {
        int idx  = bid * 256 + t;
        int pair = idx >> 18;
        int q    = (idx >> 7) & (SEQ - 1);
        int hd   = idx & (HD - 1);
        int row  = pair * SEQ + q;
        float osum = 0.f, ls = 0.f;
        for (int z = 0; z < NSPLIT; ++z) {
            ls   += lsum[z * ROWS_P + row];
            osum += b2f(Opart[(size_t)z * OPART_ELEMS + (size_t)row * HD + hd]);
        }
        int b = pair / 6, h = pair % 6;
        att[((size_t)(b * SEQ + q)) * DMODEL + h * HD + hd] = f2b(osum / ls);
    } else {
        int gb   = bid - MERGE_BLOCKS;
        int pair = gb >> 9;               // 0..3
        int q    = (gb & 511) * 4 + wave;
        int b    = pair >> 1;
        int h    = 10 + (pair & 1);

        const short* base = qkv + (size_t)b * SEQ * QKVROW;
        const short* qp   = base + (size_t)q * QKVROW + h * HD;
        const short* k0   = base + DMODEL + h * HD;
        const short* k1   = base + (size_t)(SEQ - 1) * QKVROW + DMODEL + h * HD;

        float s0 = fmaf(b2f(qp[lane]), b2f(k0[lane]),
                   b2f(qp[lane + 64]) * b2f(k0[lane + 64]));
        float s1 = fmaf(b2f(qp[lane]), b2f(k1[lane]),
                   b2f(qp[lane + 64]) * b2f(k1[lane + 64]));
        for (int off = 1; off < 64; off <<= 1) {
            s0 += __shfl_xor(s0, off, 64);
            s1 += __shfl_xor(s1, off, 64);
        }
        s0 *= SCALE; s1 *= SCALE;
        float m  = fmaxf(s0, s1);
        float e0 = __expf(s0 - m), e1 = __expf(s1 - m);
        float inv = 1.f / (e0 + e1);
        float p0 = e0 * inv, p1 = e1 * inv;

        const short* v0 = base + 2 * DMODEL + h * HD;
        const short* v1 = base + (size_t)(SEQ - 1) * QKVROW + 2 * DMODEL + h * HD;
        size_t ob = ((size_t)(b * SEQ + q)) * DMODEL + h * HD;
        att[ob + lane]      = f2b(fmaf(p0, b2f(v0[lane]),      p1 * b2f(v1[lane])));
        att[ob + lane + 64] = f2b(fmaf(p0, b2f(v0[lane + 64]), p1 * b2f(v1[lane + 64])));
    }
}

// ---------------------------------------------------------------------------
extern "C" void kernel_launch(void* const* d_in, const int* in_sizes, int n_in,
                              void* d_out, int out_size, void* d_ws, size_t ws_size,
                              hipStream_t stream) {
    const float* x    = (const float*)d_in[0];
    const float* Wqkv = (const float*)d_in[1];
    const float* bqkv = (const float*)d_in[2];
    const float* Wout = (const float*)d_in[3];
    const float* bout = (const float*)d_in[4];

    // ws layout (~94.8 MB): att aliases xb (xb dead after GEMM1);
    // vT (6.3 MB, V^T of full heads) aliases WqkvT (dead after GEMM1).
    char* p = (char*)d_ws;
    short* qkv   = (short*)p;  p += (size_t)TOK * QKVROW * 2;      // 37.75 MB
    short* Opart = (short*)p;  p += OPART_ELEMS * NSPLIT * 2;      // 25.17 MB
    float* lsum  = (float*)p;  p += (size_t)ROWS_P * NSPLIT * 4;   // 0.39 MB
    short* xb    = (short*)p;  p += (size_t)TOK * DMODEL * 2;      // 12.58 MB
    short* att   = xb;                                             // alias
    short* WqkvT = (short*)p;  p += (size_t)QKVROW * DMODEL * 2;   // 14.16 MB
    short* vT    = WqkvT;                                          // alias (6.29 MB used)
    short* WoutT = (short*)p;                                      // 4.72 MB

    // 0) fused prepass
    prepass_k<<<dim3(CVT_BLOCKS + TQKV_BLOCKS + TOUT_BLOCKS), 256, 0, stream>>>(
        x, Wqkv, Wout, xb, WqkvT, WoutT);
    // 1) QKV = x @ Wqkv + bqkv   (bf16 out)
    gemm_tn_k<true><<<dim3(QKVROW / 128, TOK / 128), 256, 0, stream>>>(
        xb, WqkvT, bqkv, (void*)qkv, TOK, QKVROW, DMODEL);
    // 2) V^T for full heads (WqkvT now dead -> reuse as vT)
    vtrans_k<<<dim3(VT_BLOCKS), 256, 0, stream>>>(qkv, vT);
    // 3) attention: full v2 + banded local MFMA + fused merge/global
    attn_full_v2<<<dim3(SEQ / 128, NPAIR, NSPLIT), 256, 0, stream>>>(
        qkv, vT, Opart, lsum);
    attn_local_mfma<<<dim3(SEQ / 64, 8), 256, 0, stream>>>(qkv, att);
    postattn_k<<<dim3(MERGE_BLOCKS + GLOBAL_BLOCKS), 256, 0, stream>>>(
        qkv, Opart, lsum, att);
    // 4) out = att @ Wout + bout  (fp32 out)
    gemm_tn_k<false><<<dim3(DMODEL / 128, TOK / 128), 256, 0, stream>>>(
        att, WoutT, bout, d_out, TOK, DMODEL, DMODEL);
}